// Round 1
// baseline (2385.652 us; speedup 1.0000x reference)
//
#include <hip/hip_runtime.h>
#include <math.h>

#define EPS 1e-8f

constexpr int B_ = 128;     // batch
constexpr int Q_ = 20;      // queries per sample
constexpr int D_ = 11;      // feature dim
constexpr int N_ = 100000;  // songs
constexpr int DP_ = 12;     // padded feature dim (3x float4)
constexpr int SCHUNK = 8;   // song chunks (grid.x of sim kernel)
constexpr int TPB = 256;
constexpr int SPI = 4;      // songs per inner iteration per thread
constexpr int CH = N_ / SCHUNK;  // 12500, divisible by SPI*... (12500 % 4 == 0)

// ---------------- MLP encoder: x[B][55] -> pnorm[B][Q][DP] (normalized, padded) ---
__global__ void mlp_kernel(const float* __restrict__ x,
                           const float* __restrict__ W1, const float* __restrict__ b1,
                           const float* __restrict__ W2, const float* __restrict__ b2,
                           const float* __restrict__ W3, const float* __restrict__ b3,
                           float* __restrict__ pnorm)
{
    __shared__ float xr[55];
    __shared__ float h1[128];
    __shared__ float h2[64];
    __shared__ float prod[220];
    const int b = blockIdx.x;
    const int t = threadIdx.x;
    if (t < 55) xr[t] = x[b * 55 + t];
    __syncthreads();
    if (t < 128) {
        float s = b1[t];
        for (int k = 0; k < 55; ++k) s += xr[k] * W1[k * 128 + t];
        h1[t] = fmaxf(s, 0.0f);
    }
    __syncthreads();
    if (t < 64) {
        float s = b2[t];
        for (int k = 0; k < 128; ++k) s += h1[k] * W2[k * 64 + t];
        h2[t] = fmaxf(s, 0.0f);
    }
    __syncthreads();
    if (t < 220) {
        float s = b3[t];
        for (int k = 0; k < 64; ++k) s += h2[k] * W3[k * 220 + t];
        prod[t] = s;
    }
    __syncthreads();
    if (t < Q_) {
        float ss = 0.0f;
        for (int d = 0; d < D_; ++d) { float v = prod[t * D_ + d]; ss += v * v; }
        float nrm = fmaxf(sqrtf(ss), EPS);
        float* o = pnorm + (b * Q_ + t) * DP_;
        for (int d = 0; d < D_; ++d) o[d] = prod[t * D_ + d] / nrm;
        o[D_] = 0.0f;
    }
}

// ---------------- song pre-normalization into padded [N][12] ----------------------
__global__ void snorm_kernel(const float* __restrict__ songs, float* __restrict__ snorm)
{
    int i = blockIdx.x * blockDim.x + threadIdx.x;
    if (i >= N_) return;
    float v[D_]; float ss = 0.0f;
    for (int d = 0; d < D_; ++d) { v[d] = songs[(size_t)i * D_ + d]; ss += v[d] * v[d]; }
    float nrm = fmaxf(sqrtf(ss), EPS);
    float* o = snorm + (size_t)i * DP_;
    for (int d = 0; d < D_; ++d) o[d] = v[d] / nrm;
    o[D_] = 0.0f;
}

// ---------------- fused sim + per-chunk argmax ------------------------------------
// grid = (SCHUNK, B_). Each block: 20 queries (one batch) x CH songs.
template<bool PRENORM>
__global__ void sim_kernel(const float* __restrict__ pnorm,
                           const float* __restrict__ sdata,
                           float* __restrict__ pval, int* __restrict__ pidx)
{
    const int chunk = blockIdx.x;
    const int b = blockIdx.y;
    const int t = threadIdx.x;
    __shared__ __align__(16) float sp[Q_ * DP_];
    __shared__ float rv4[4][Q_];
    __shared__ int   ri4[4][Q_];
    for (int j = t; j < Q_ * DP_; j += TPB) sp[j] = pnorm[b * Q_ * DP_ + j];
    __syncthreads();

    float bestv[Q_];
    int   besti[Q_];
#pragma unroll
    for (int q = 0; q < Q_; ++q) { bestv[q] = -1e30f; besti[q] = 0; }

    const int cbase = chunk * CH;
    const int cend  = cbase + CH;
    for (int i0 = cbase + t * SPI; i0 < cend; i0 += TPB * SPI) {
        float sv[SPI][DP_];
        if (PRENORM) {
#pragma unroll
            for (int s = 0; s < SPI; ++s) {
                const float4* p4 = reinterpret_cast<const float4*>(sdata + (size_t)(i0 + s) * DP_);
                float4 a = p4[0], c = p4[1], e = p4[2];
                sv[s][0] = a.x; sv[s][1] = a.y; sv[s][2]  = a.z; sv[s][3]  = a.w;
                sv[s][4] = c.x; sv[s][5] = c.y; sv[s][6]  = c.z; sv[s][7]  = c.w;
                sv[s][8] = e.x; sv[s][9] = e.y; sv[s][10] = e.z; sv[s][11] = e.w;
            }
        } else {
#pragma unroll
            for (int s = 0; s < SPI; ++s) {
                float raw[D_]; float ss = 0.0f;
#pragma unroll
                for (int d = 0; d < D_; ++d) { raw[d] = sdata[(size_t)(i0 + s) * D_ + d]; ss += raw[d] * raw[d]; }
                float nrm = fmaxf(sqrtf(ss), EPS);
#pragma unroll
                for (int d = 0; d < D_; ++d) sv[s][d] = raw[d] / nrm;
                sv[s][D_] = 0.0f;
            }
        }
#pragma unroll
        for (int q = 0; q < Q_; ++q) {
            const float4* q4 = reinterpret_cast<const float4*>(&sp[q * DP_]);
            const float4 A = q4[0], Bv = q4[1], Cv = q4[2];
            float acc[SPI];
#pragma unroll
            for (int s = 0; s < SPI; ++s) {
                float a;
                a  = sv[s][0]  * A.x;   // sequential d=0..10, matches ref accumulation closely
                a += sv[s][1]  * A.y;
                a += sv[s][2]  * A.z;
                a += sv[s][3]  * A.w;
                a += sv[s][4]  * Bv.x;
                a += sv[s][5]  * Bv.y;
                a += sv[s][6]  * Bv.z;
                a += sv[s][7]  * Bv.w;
                a += sv[s][8]  * Cv.x;
                a += sv[s][9]  * Cv.y;
                a += sv[s][10] * Cv.z;
                acc[s] = a;
            }
#pragma unroll
            for (int s = 0; s < SPI; ++s) {
                // strictly-greater keeps FIRST max index (numpy argmax semantics)
                if (acc[s] > bestv[q]) { bestv[q] = acc[s]; besti[q] = i0 + s; }
            }
        }
    }

    // wave-level butterfly reduction (val, idx) with first-index tie-break
    const int lane = t & 63;
    const int wv = t >> 6;
#pragma unroll
    for (int q = 0; q < Q_; ++q) {
        float v = bestv[q]; int ix = besti[q];
#pragma unroll
        for (int off = 1; off < 64; off <<= 1) {
            float v2 = __shfl_xor(v, off, 64);
            int   i2 = __shfl_xor(ix, off, 64);
            if (v2 > v || (v2 == v && i2 < ix)) { v = v2; ix = i2; }
        }
        if (lane == 0) { rv4[wv][q] = v; ri4[wv][q] = ix; }
    }
    __syncthreads();
    if (t < Q_) {
        float v = rv4[0][t]; int ix = ri4[0][t];
#pragma unroll
        for (int w = 1; w < 4; ++w) {
            float v2 = rv4[w][t]; int i2 = ri4[w][t];
            if (v2 > v || (v2 == v && i2 < ix)) { v = v2; ix = i2; }
        }
        pval[(b * Q_ + t) * SCHUNK + chunk] = v;
        pidx[(b * Q_ + t) * SCHUNK + chunk] = ix;
    }
}

// ---------------- final reduce over chunks + gather songs[best] -------------------
__global__ void final_kernel(const float* __restrict__ pval, const int* __restrict__ pidx,
                             const float* __restrict__ songs, float* __restrict__ out)
{
    int j = blockIdx.x * blockDim.x + threadIdx.x;
    if (j >= B_ * Q_) return;
    float bv = -1e30f; int bi = 0;
#pragma unroll
    for (int s = 0; s < SCHUNK; ++s) {
        float v = pval[j * SCHUNK + s]; int ix = pidx[j * SCHUNK + s];
        if (v > bv || (v == bv && ix < bi)) { bv = v; bi = ix; }
    }
    for (int d = 0; d < D_; ++d) out[j * D_ + d] = songs[(size_t)bi * D_ + d];
}

extern "C" void kernel_launch(void* const* d_in, const int* in_sizes, int n_in,
                              void* d_out, int out_size, void* d_ws, size_t ws_size,
                              hipStream_t stream)
{
    const float* x     = (const float*)d_in[0];
    const float* W1    = (const float*)d_in[1];
    const float* b1    = (const float*)d_in[2];
    const float* W2    = (const float*)d_in[3];
    const float* b2    = (const float*)d_in[4];
    const float* W3    = (const float*)d_in[5];
    const float* b3    = (const float*)d_in[6];
    const float* songs = (const float*)d_in[7];
    float* out = (float*)d_out;

    float* pnorm = (float*)d_ws;                               // B*Q*DP floats
    float* snorm = pnorm + B_ * Q_ * DP_;                      // N*DP floats
    const size_t need_full =
        ((size_t)B_ * Q_ * DP_ + (size_t)N_ * DP_ + 2ull * B_ * Q_ * SCHUNK) * sizeof(float);
    const bool prenorm = (ws_size >= need_full);

    float* pval;
    if (prenorm) pval = snorm + (size_t)N_ * DP_;
    else         pval = pnorm + B_ * Q_ * DP_;
    int* pidx = (int*)(pval + B_ * Q_ * SCHUNK);

    mlp_kernel<<<B_, 256, 0, stream>>>(x, W1, b1, W2, b2, W3, b3, pnorm);
    if (prenorm) {
        snorm_kernel<<<(N_ + 255) / 256, 256, 0, stream>>>(songs, snorm);
        sim_kernel<true><<<dim3(SCHUNK, B_), TPB, 0, stream>>>(pnorm, snorm, pval, pidx);
    } else {
        sim_kernel<false><<<dim3(SCHUNK, B_), TPB, 0, stream>>>(pnorm, songs, pval, pidx);
    }
    final_kernel<<<(B_ * Q_ + TPB - 1) / TPB, TPB, 0, stream>>>(pval, pidx, songs, out);
}

// Round 2
// 187.109 us; speedup vs baseline: 12.7501x; 12.7501x over previous
//
#include <hip/hip_runtime.h>
#include <math.h>

#define EPS 1e-8f

constexpr int B_ = 128;     // batch
constexpr int Q_ = 20;      // queries per sample
constexpr int D_ = 11;      // feature dim
constexpr int N_ = 100000;  // songs
constexpr int DP_ = 12;     // padded feature dim (3x float4)
constexpr int TPB = 256;
constexpr int NPAIR = B_ * Q_;  // 2560

// ---------------- MLP encoder: x[B][55] -> pnorm[B][Q][DP] (normalized, padded) ---
__global__ void mlp_kernel(const float* __restrict__ x,
                           const float* __restrict__ W1, const float* __restrict__ b1,
                           const float* __restrict__ W2, const float* __restrict__ b2,
                           const float* __restrict__ W3, const float* __restrict__ b3,
                           float* __restrict__ pnorm)
{
    __shared__ float xr[55];
    __shared__ float h1[128];
    __shared__ float h2[64];
    __shared__ float prod[220];
    const int b = blockIdx.x;
    const int t = threadIdx.x;
    if (t < 55) xr[t] = x[b * 55 + t];
    __syncthreads();
    if (t < 128) {
        float s = b1[t];
        for (int k = 0; k < 55; ++k) s += xr[k] * W1[k * 128 + t];
        h1[t] = fmaxf(s, 0.0f);
    }
    __syncthreads();
    if (t < 64) {
        float s = b2[t];
        for (int k = 0; k < 128; ++k) s += h1[k] * W2[k * 64 + t];
        h2[t] = fmaxf(s, 0.0f);
    }
    __syncthreads();
    if (t < 220) {
        float s = b3[t];
        for (int k = 0; k < 64; ++k) s += h2[k] * W3[k * 220 + t];
        prod[t] = s;
    }
    __syncthreads();
    if (t < Q_) {
        float ss = 0.0f;
        for (int d = 0; d < D_; ++d) { float v = prod[t * D_ + d]; ss += v * v; }
        float nrm = fmaxf(sqrtf(ss), EPS);
        float* o = pnorm + (b * Q_ + t) * DP_;
        for (int d = 0; d < D_; ++d) o[d] = prod[t * D_ + d] / nrm;
        o[D_] = 0.0f;
    }
}

// ---------------- song pre-normalization into padded [N][12] ----------------------
__global__ void snorm_kernel(const float* __restrict__ songs, float* __restrict__ snorm)
{
    int i = blockIdx.x * blockDim.x + threadIdx.x;
    if (i >= N_) return;
    float v[D_]; float ss = 0.0f;
#pragma unroll
    for (int d = 0; d < D_; ++d) { v[d] = songs[(size_t)i * D_ + d]; ss += v[d] * v[d]; }
    float nrm = fmaxf(sqrtf(ss), EPS);
    float* o = snorm + (size_t)i * DP_;
#pragma unroll
    for (int d = 0; d < D_; ++d) o[d] = v[d] / nrm;
    o[D_] = 0.0f;
}

// ---------------- sim + per-chunk argmax, query-per-lane layout -------------------
// grid = (NCH, NPAIR/TPB). Lane owns one (b,q) pair; song address is wave-uniform
// (derived only from blockIdx.x + loop counter) -> scalar loads, zero LDS, tiny
// statically-indexed register state (no scratch possible).
template<bool PRENORM, int NCH>
__global__ void sim2_kernel(const float* __restrict__ pnorm,
                            const float* __restrict__ sdata,   // snorm [N][12] or songs [N][11]
                            float* __restrict__ pval, int* __restrict__ pidx)
{
    constexpr int CS = N_ / NCH;   // songs per chunk
    const int chunk = blockIdx.x;
    const int j = blockIdx.y * TPB + threadIdx.x;   // pair id (b*Q+q)

    float qv[D_];
#pragma unroll
    for (int d = 0; d < D_; ++d) qv[d] = pnorm[j * DP_ + d];

    float bestv = -1e30f;
    int   besti = 0;
    const int base = chunk * CS;
    for (int i = base; i < base + CS; i += 4) {
        float acc[4];
#pragma unroll
        for (int u = 0; u < 4; ++u) {
            float sv[D_];
            if (PRENORM) {
#pragma unroll
                for (int d = 0; d < D_; ++d) sv[d] = sdata[(size_t)(i + u) * DP_ + d];
            } else {
                float ss = 0.0f;
#pragma unroll
                for (int d = 0; d < D_; ++d) { sv[d] = sdata[(size_t)(i + u) * D_ + d]; ss += sv[d] * sv[d]; }
                float nrm = fmaxf(sqrtf(ss), EPS);
#pragma unroll
                for (int d = 0; d < D_; ++d) sv[d] /= nrm;
            }
            // sequential d=0..10: same accumulation order as the reference einsum
            float a = qv[0] * sv[0];
#pragma unroll
            for (int d = 1; d < D_; ++d) a += qv[d] * sv[d];
            acc[u] = a;
        }
#pragma unroll
        for (int u = 0; u < 4; ++u) {
            // strictly-greater + ascending i: numpy first-index argmax semantics
            if (acc[u] > bestv) { bestv = acc[u]; besti = i + u; }
        }
    }
    pval[(size_t)j * NCH + chunk] = bestv;
    pidx[(size_t)j * NCH + chunk] = besti;
}

// ---------------- final reduce over chunks + gather: one wave per pair ------------
template<int NCH>
__global__ void final2_kernel(const float* __restrict__ pval, const int* __restrict__ pidx,
                              const float* __restrict__ songs, float* __restrict__ out)
{
    const int pair = blockIdx.x * (TPB / 64) + (threadIdx.x >> 6);
    const int lane = threadIdx.x & 63;
    float v = -1e30f; int ix = 0x7fffffff;
#pragma unroll
    for (int k = 0; k < (NCH + 63) / 64; ++k) {
        int c = lane + k * 64;
        if (c < NCH) {
            float v2 = pval[(size_t)pair * NCH + c];
            int   i2 = pidx[(size_t)pair * NCH + c];
            if (v2 > v || (v2 == v && i2 < ix)) { v = v2; ix = i2; }
        }
    }
#pragma unroll
    for (int off = 1; off < 64; off <<= 1) {
        float v2 = __shfl_xor(v, off, 64);
        int   i2 = __shfl_xor(ix, off, 64);
        if (v2 > v || (v2 == v && i2 < ix)) { v = v2; ix = i2; }
    }
    if (lane < D_) out[(size_t)pair * D_ + lane] = songs[(size_t)ix * D_ + lane];
}

extern "C" void kernel_launch(void* const* d_in, const int* in_sizes, int n_in,
                              void* d_out, int out_size, void* d_ws, size_t ws_size,
                              hipStream_t stream)
{
    const float* x     = (const float*)d_in[0];
    const float* W1    = (const float*)d_in[1];
    const float* b1    = (const float*)d_in[2];
    const float* W2    = (const float*)d_in[3];
    const float* b2    = (const float*)d_in[4];
    const float* W3    = (const float*)d_in[5];
    const float* b3    = (const float*)d_in[6];
    const float* songs = (const float*)d_in[7];
    float* out = (float*)d_out;

    float* pnorm = (float*)d_ws;                            // NPAIR*DP floats
    constexpr size_t PN = (size_t)NPAIR * DP_;
    constexpr size_t SN = (size_t)N_ * DP_;

    // tiered workspace plan
    const size_t need_full  = (PN + SN + 2ull * NPAIR * 250) * sizeof(float);
    const size_t need_mid   = (PN + 2ull * NPAIR * 250) * sizeof(float);

    mlp_kernel<<<B_, 256, 0, stream>>>(x, W1, b1, W2, b2, W3, b3, pnorm);

    if (ws_size >= need_full) {
        constexpr int NCH = 250;
        float* snorm = pnorm + PN;
        float* pval  = snorm + SN;
        int*   pidx  = (int*)(pval + (size_t)NPAIR * NCH);
        snorm_kernel<<<(N_ + 255) / 256, 256, 0, stream>>>(songs, snorm);
        sim2_kernel<true, NCH><<<dim3(NCH, NPAIR / TPB), TPB, 0, stream>>>(pnorm, snorm, pval, pidx);
        final2_kernel<NCH><<<NPAIR / (TPB / 64), TPB, 0, stream>>>(pval, pidx, songs, out);
    } else if (ws_size >= need_mid) {
        constexpr int NCH = 250;
        float* pval = pnorm + PN;
        int*   pidx = (int*)(pval + (size_t)NPAIR * NCH);
        sim2_kernel<false, NCH><<<dim3(NCH, NPAIR / TPB), TPB, 0, stream>>>(pnorm, songs, pval, pidx);
        final2_kernel<NCH><<<NPAIR / (TPB / 64), TPB, 0, stream>>>(pval, pidx, songs, out);
    } else {
        constexpr int NCH = 50;   // partials only 1 MB
        float* pval = pnorm + PN;
        int*   pidx = (int*)(pval + (size_t)NPAIR * NCH);
        sim2_kernel<false, NCH><<<dim3(NCH, NPAIR / TPB), TPB, 0, stream>>>(pnorm, songs, pval, pidx);
        final2_kernel<NCH><<<NPAIR / (TPB / 64), TPB, 0, stream>>>(pval, pidx, songs, out);
    }
}

// Round 3
// 133.396 us; speedup vs baseline: 17.8839x; 1.4027x over previous
//
#include <hip/hip_runtime.h>
#include <math.h>

#define EPS 1e-8f

constexpr int B_ = 128;     // batch
constexpr int Q_ = 20;      // queries per sample
constexpr int D_ = 11;      // feature dim
constexpr int N_ = 100000;  // songs
constexpr int DP_ = 12;     // padded feature dim (3x float4)
constexpr int TPB = 256;
constexpr int NPAIR = B_ * Q_;  // 2560

// ---------------- MLP encoder: x[B][55] -> pnorm[B][Q][DP] (normalized, padded) ---
__global__ void mlp_kernel(const float* __restrict__ x,
                           const float* __restrict__ W1, const float* __restrict__ b1,
                           const float* __restrict__ W2, const float* __restrict__ b2,
                           const float* __restrict__ W3, const float* __restrict__ b3,
                           float* __restrict__ pnorm)
{
    __shared__ float xr[55];
    __shared__ float h1[128];
    __shared__ float h2[64];
    __shared__ float prod[220];
    const int b = blockIdx.x;
    const int t = threadIdx.x;
    if (t < 55) xr[t] = x[b * 55 + t];
    __syncthreads();
    if (t < 128) {
        float s = b1[t];
        for (int k = 0; k < 55; ++k) s += xr[k] * W1[k * 128 + t];
        h1[t] = fmaxf(s, 0.0f);
    }
    __syncthreads();
    if (t < 64) {
        float s = b2[t];
        for (int k = 0; k < 128; ++k) s += h1[k] * W2[k * 64 + t];
        h2[t] = fmaxf(s, 0.0f);
    }
    __syncthreads();
    if (t < 220) {
        float s = b3[t];
        for (int k = 0; k < 64; ++k) s += h2[k] * W3[k * 220 + t];
        prod[t] = s;
    }
    __syncthreads();
    if (t < Q_) {
        float ss = 0.0f;
        for (int d = 0; d < D_; ++d) { float v = prod[t * D_ + d]; ss += v * v; }
        float nrm = fmaxf(sqrtf(ss), EPS);
        float* o = pnorm + (b * Q_ + t) * DP_;
        for (int d = 0; d < D_; ++d) o[d] = prod[t * D_ + d] / nrm;
        o[D_] = 0.0f;
    }
}

// ---------------- song pre-normalization into padded [N][12] ----------------------
__global__ void snorm_kernel(const float* __restrict__ songs, float* __restrict__ snorm)
{
    int i = blockIdx.x * blockDim.x + threadIdx.x;
    if (i >= N_) return;
    float v[DP_]; float ss = 0.0f;
#pragma unroll
    for (int d = 0; d < D_; ++d) { v[d] = songs[(size_t)i * D_ + d]; ss += v[d] * v[d]; }
    float nrm = fmaxf(sqrtf(ss), EPS);
#pragma unroll
    for (int d = 0; d < D_; ++d) v[d] /= nrm;
    v[D_] = 0.0f;
    float4* o = reinterpret_cast<float4*>(snorm + (size_t)i * DP_);
    o[0] = make_float4(v[0], v[1], v[2], v[3]);
    o[1] = make_float4(v[4], v[5], v[6], v[7]);
    o[2] = make_float4(v[8], v[9], v[10], v[11]);
}

// dot over 11 dims, fixed fmaf sequence (deterministic, identical at every call site)
__device__ __forceinline__ float dot11(const float* __restrict__ q,
                                       const float4 a, const float4 b, const float4 c)
{
    float x = q[0] * a.x;
    x = fmaf(q[1], a.y, x);
    x = fmaf(q[2], a.z, x);
    x = fmaf(q[3], a.w, x);
    x = fmaf(q[4], b.x, x);
    x = fmaf(q[5], b.y, x);
    x = fmaf(q[6], b.z, x);
    x = fmaf(q[7], b.w, x);
    x = fmaf(q[8], c.x, x);
    x = fmaf(q[9], c.y, x);
    x = fmaf(q[10], c.z, x);
    return x;
}

// ---------------- sim + per-chunk argmax, 2 pairs/thread, deferred index ----------
// grid = (NCH, NPAIR/(2*TPB)). Lane owns two (b,q) pairs; song address wave-uniform.
template<int NCH>
__global__ __launch_bounds__(TPB, 3)
void sim3_kernel(const float* __restrict__ pnorm,
                 const float* __restrict__ snorm,
                 float* __restrict__ pval, int* __restrict__ pidx)
{
    constexpr int CS = N_ / NCH;   // songs per chunk (400 for NCH=250)
    constexpr int NG = CS / 4;     // 4-song groups per chunk
    const int chunk = blockIdx.x;
    const int t = threadIdx.x;
    const int j0 = blockIdx.y * (2 * TPB) + t;
    const int j1 = j0 + TPB;

    float qa[D_], qb[D_];
#pragma unroll
    for (int d = 0; d < D_; ++d) qa[d] = pnorm[j0 * DP_ + d];
#pragma unroll
    for (int d = 0; d < D_; ++d) qb[d] = pnorm[j1 * DP_ + d];

    float bva = -1e30f, bvb = -1e30f;
    int   ga = 0, gb = 0;

    const float4* s4 = reinterpret_cast<const float4*>(snorm) + (size_t)chunk * CS * 3;

#pragma unroll 2
    for (int g = 0; g < NG; ++g) {
        float4 v[12];
#pragma unroll
        for (int k = 0; k < 12; ++k) v[k] = s4[g * 12 + k];
        float aa[4], ab[4];
#pragma unroll
        for (int u = 0; u < 4; ++u) {
            aa[u] = dot11(qa, v[u * 3 + 0], v[u * 3 + 1], v[u * 3 + 2]);
            ab[u] = dot11(qb, v[u * 3 + 0], v[u * 3 + 1], v[u * 3 + 2]);
        }
        float ma = fmaxf(fmaxf(fmaxf(aa[0], aa[1]), aa[2]), aa[3]);  // fuses to v_max3
        float mb = fmaxf(fmaxf(fmaxf(ab[0], ab[1]), ab[2]), ab[3]);
        // strictly-greater keeps FIRST group (numpy first-index argmax)
        if (ma > bva) { bva = ma; ga = g; }
        if (mb > bvb) { bvb = mb; gb = g; }
    }

    // Recompute winning group with the identical fmaf sequence -> bit-exact match;
    // reverse scan picks the FIRST in-group index achieving the max.
    int ia, ib;
    {
        const float4* vg = s4 + (size_t)ga * 12;
        float acc[4];
#pragma unroll
        for (int u = 0; u < 4; ++u) acc[u] = dot11(qa, vg[u * 3 + 0], vg[u * 3 + 1], vg[u * 3 + 2]);
        int r = chunk * CS + ga * 4;
        ia = r;
#pragma unroll
        for (int u = 3; u >= 0; --u) if (acc[u] == bva) ia = r + u;
    }
    {
        const float4* vg = s4 + (size_t)gb * 12;
        float acc[4];
#pragma unroll
        for (int u = 0; u < 4; ++u) acc[u] = dot11(qb, vg[u * 3 + 0], vg[u * 3 + 1], vg[u * 3 + 2]);
        int r = chunk * CS + gb * 4;
        ib = r;
#pragma unroll
        for (int u = 3; u >= 0; --u) if (acc[u] == bvb) ib = r + u;
    }

    // [chunk][pair] layout: adjacent lanes -> adjacent addresses (full-line writes)
    pval[(size_t)chunk * NPAIR + j0] = bva;
    pidx[(size_t)chunk * NPAIR + j0] = ia;
    pval[(size_t)chunk * NPAIR + j1] = bvb;
    pidx[(size_t)chunk * NPAIR + j1] = ib;
}

// ---------------- fallback (no snorm workspace): normalize on the fly ------------
template<int NCH>
__global__ void sim2f_kernel(const float* __restrict__ pnorm,
                             const float* __restrict__ songs,
                             float* __restrict__ pval, int* __restrict__ pidx)
{
    constexpr int CS = N_ / NCH;
    const int chunk = blockIdx.x;
    const int j = blockIdx.y * TPB + threadIdx.x;

    float qv[D_];
#pragma unroll
    for (int d = 0; d < D_; ++d) qv[d] = pnorm[j * DP_ + d];

    float bestv = -1e30f;
    int   besti = 0;
    const int base = chunk * CS;
    for (int i = base; i < base + CS; ++i) {
        float sv[D_]; float ss = 0.0f;
#pragma unroll
        for (int d = 0; d < D_; ++d) { sv[d] = songs[(size_t)i * D_ + d]; ss += sv[d] * sv[d]; }
        float nrm = fmaxf(sqrtf(ss), EPS);
        float a = qv[0] * (sv[0] / nrm);
#pragma unroll
        for (int d = 1; d < D_; ++d) a = fmaf(qv[d], sv[d] / nrm, a);
        if (a > bestv) { bestv = a; besti = i; }
    }
    pval[(size_t)chunk * NPAIR + j] = bestv;
    pidx[(size_t)chunk * NPAIR + j] = besti;
}

// ---------------- final reduce over chunks + gather: one wave per pair ------------
template<int NCH>
__global__ void final2_kernel(const float* __restrict__ pval, const int* __restrict__ pidx,
                              const float* __restrict__ songs, float* __restrict__ out)
{
    const int pair = blockIdx.x * (TPB / 64) + (threadIdx.x >> 6);
    const int lane = threadIdx.x & 63;
    float v = -1e30f; int ix = 0x7fffffff;
#pragma unroll
    for (int k = 0; k < (NCH + 63) / 64; ++k) {
        int c = lane + k * 64;
        if (c < NCH) {
            float v2 = pval[(size_t)c * NPAIR + pair];
            int   i2 = pidx[(size_t)c * NPAIR + pair];
            if (v2 > v || (v2 == v && i2 < ix)) { v = v2; ix = i2; }
        }
    }
#pragma unroll
    for (int off = 1; off < 64; off <<= 1) {
        float v2 = __shfl_xor(v, off, 64);
        int   i2 = __shfl_xor(ix, off, 64);
        if (v2 > v || (v2 == v && i2 < ix)) { v = v2; ix = i2; }
    }
    if (lane < D_) out[(size_t)pair * D_ + lane] = songs[(size_t)ix * D_ + lane];
}

extern "C" void kernel_launch(void* const* d_in, const int* in_sizes, int n_in,
                              void* d_out, int out_size, void* d_ws, size_t ws_size,
                              hipStream_t stream)
{
    const float* x     = (const float*)d_in[0];
    const float* W1    = (const float*)d_in[1];
    const float* b1    = (const float*)d_in[2];
    const float* W2    = (const float*)d_in[3];
    const float* b2    = (const float*)d_in[4];
    const float* W3    = (const float*)d_in[5];
    const float* b3    = (const float*)d_in[6];
    const float* songs = (const float*)d_in[7];
    float* out = (float*)d_out;

    float* pnorm = (float*)d_ws;                            // NPAIR*DP floats
    constexpr size_t PN = (size_t)NPAIR * DP_;
    constexpr size_t SN = (size_t)N_ * DP_;
    constexpr int NCH = 250;

    const size_t need_full = (PN + SN + 2ull * NPAIR * NCH) * sizeof(float);
    const size_t need_mid  = (PN + 2ull * NPAIR * NCH) * sizeof(float);

    mlp_kernel<<<B_, 256, 0, stream>>>(x, W1, b1, W2, b2, W3, b3, pnorm);

    if (ws_size >= need_full) {
        float* snorm = pnorm + PN;
        float* pval  = snorm + SN;
        int*   pidx  = (int*)(pval + (size_t)NPAIR * NCH);
        snorm_kernel<<<(N_ + 255) / 256, 256, 0, stream>>>(songs, snorm);
        sim3_kernel<NCH><<<dim3(NCH, NPAIR / (2 * TPB)), TPB, 0, stream>>>(pnorm, snorm, pval, pidx);
        final2_kernel<NCH><<<NPAIR / (TPB / 64), TPB, 0, stream>>>(pval, pidx, songs, out);
    } else if (ws_size >= need_mid) {
        float* pval = pnorm + PN;
        int*   pidx = (int*)(pval + (size_t)NPAIR * NCH);
        sim2f_kernel<NCH><<<dim3(NCH, NPAIR / TPB), TPB, 0, stream>>>(pnorm, songs, pval, pidx);
        final2_kernel<NCH><<<NPAIR / (TPB / 64), TPB, 0, stream>>>(pval, pidx, songs, out);
    } else {
        constexpr int NCH2 = 50;
        float* pval = pnorm + PN;
        int*   pidx = (int*)(pval + (size_t)NPAIR * NCH2);
        sim2f_kernel<NCH2><<<dim3(NCH2, NPAIR / TPB), TPB, 0, stream>>>(pnorm, songs, pval, pidx);
        final2_kernel<NCH2><<<NPAIR / (TPB / 64), TPB, 0, stream>>>(pval, pidx, songs, out);
    }
}